// Round 2
// baseline (615.894 us; speedup 1.0000x reference)
//
#include <hip/hip_runtime.h>
#include <hip/hip_bf16.h>

#define BB 4
#define TT 256
#define UU 100
#define U1 101
#define VV 1024

__device__ __forceinline__ float lse2(float x, float y) {
    float m = fmaxf(x, y);
    float n = fminf(x, y);
    return m + __logf(1.0f + __expf(n - m));
}

__device__ __forceinline__ float max16(const float4& a, const float4& b,
                                       const float4& c, const float4& d) {
    float m0 = fmaxf(fmaxf(a.x, a.y), fmaxf(a.z, a.w));
    float m1 = fmaxf(fmaxf(b.x, b.y), fmaxf(b.z, b.w));
    float m2 = fmaxf(fmaxf(c.x, c.y), fmaxf(c.z, c.w));
    float m3 = fmaxf(fmaxf(d.x, d.y), fmaxf(d.z, d.w));
    return fmaxf(fmaxf(m0, m1), fmaxf(m2, m3));
}

__device__ __forceinline__ float sumexp16(const float4& a, const float4& b,
                                          const float4& c, const float4& d, float m) {
    return __expf(a.x - m) + __expf(a.y - m) + __expf(a.z - m) + __expf(a.w - m)
         + __expf(b.x - m) + __expf(b.y - m) + __expf(b.z - m) + __expf(b.w - m)
         + __expf(c.x - m) + __expf(c.y - m) + __expf(c.z - m) + __expf(c.w - m)
         + __expf(d.x - m) + __expf(d.y - m) + __expf(d.z - m) + __expf(d.w - m);
}

// ---------------- Kernel 1: one wave handles TWO cells (t, t+1) at the same u.
// 8 outstanding dwordx4/lane; single merged (max,sum) butterfly per cell.
__global__ __launch_bounds__(256) void k_lse(const float* __restrict__ logits,
                                             const int* __restrict__ targets,
                                             float* __restrict__ lpB,
                                             float* __restrict__ lpE) {
    const int NW = BB * (TT / 2) * U1;                 // waves total
    int wid  = (blockIdx.x << 2) | (threadIdx.x >> 6);
    int lane = threadIdx.x & 63;
    if (wid >= NW) return;
    int u  = wid % U1;
    int r  = wid / U1;
    int th = r % (TT / 2);
    int b  = r / (TT / 2);
    int t  = th * 2;

    const float* base0 = logits + ((size_t)(b * TT + t) * U1 + u) * VV;
    const float* base1 = base0 + (size_t)U1 * VV;

    int tgt = targets[b * UU + min(u, UU - 1)];
    tgt = min(max(tgt, 0), VV - 1);
    float xb0 = base0[0], xt0 = base0[tgt];
    float xb1 = base1[0], xt1 = base1[tgt];

    const float4* p0 = (const float4*)base0;
    const float4* p1 = (const float4*)base1;
    float4 a0 = p0[lane], a1 = p0[lane + 64], a2 = p0[lane + 128], a3 = p0[lane + 192];
    float4 c0 = p1[lane], c1 = p1[lane + 64], c2 = p1[lane + 128], c3 = p1[lane + 192];

    float m0 = max16(a0, a1, a2, a3);
    float m1 = max16(c0, c1, c2, c3);
    float s0 = sumexp16(a0, a1, a2, a3, m0);
    float s1 = sumexp16(c0, c1, c2, c3, m1);

#pragma unroll
    for (int off = 32; off > 0; off >>= 1) {
        float mo0 = __shfl_xor(m0, off), so0 = __shfl_xor(s0, off);
        float mo1 = __shfl_xor(m1, off), so1 = __shfl_xor(s1, off);
        float M0 = fmaxf(m0, mo0);
        s0 = s0 * __expf(m0 - M0) + so0 * __expf(mo0 - M0);
        m0 = M0;
        float M1 = fmaxf(m1, mo1);
        s1 = s1 * __expf(m1 - M1) + so1 * __expf(mo1 - M1);
        m1 = M1;
    }
    float lse0 = m0 + __logf(s0);
    float lse1 = m1 + __logf(s1);

    if (lane == 0) {
        int o = (b * U1 + u) * TT + t;                 // transposed [b][u][t], t even
        *(float2*)(lpB + o) = make_float2(xb0 - lse0, xb1 - lse1);
        if (u < UU) *(float2*)(lpE + o) = make_float2(xt0 - lse0, xt1 - lse1);
    }
}

// ---------------- Kernel 2: anti-diagonal wavefront DP, one wave per batch, 2 columns/lane
#define PF 8
__global__ __launch_bounds__(64) void k_dp(const float* __restrict__ lpB,
                                           const float* __restrict__ lpE,
                                           const int* __restrict__ tlen,
                                           const int* __restrict__ ulen,
                                           float* __restrict__ out) {
    const int b    = blockIdx.x;
    const int lane = threadIdx.x;
    const int Tb = tlen[b];
    const int Ub = ulen[b];
    const float* Bb = lpB + b * U1 * TT;
    const float* Eb = lpE + b * U1 * TT;
    const int u0 = lane * 2, u1 = u0 + 1;
    const float NEG = -1e30f;

    const int rB0 = min(u0, U1 - 1) * TT;
    const int rB1 = min(u1, U1 - 1) * TT;
    const int rE0 = min(max(u0 - 1, 0), UU - 1) * TT;
    const int rE1 = min(u0, UU - 1) * TT;

    auto cl = [](int x) { return x < 0 ? 0 : (x > TT - 1 ? TT - 1 : x); };

    float aLo = (lane == 0) ? 0.0f : NEG;
    float aHi = NEG;
    float aHiLeft = NEG;

    float fB0[PF], fB1[PF], fE0[PF], fE1[PF];
#pragma unroll
    for (int j = 0; j < PF; ++j) {
        int d = 1 + j;
        fB0[j] = Bb[rB0 + cl(d - 1 - u0)];
        fB1[j] = Bb[rB1 + cl(d - 1 - u1)];
        fE0[j] = Eb[rE0 + cl(d - u0)];
        fE1[j] = Eb[rE1 + cl(d - 1 - u0)];
    }

    const int D = Tb - 1 + Ub;
    for (int dbase = 1; dbase <= D; dbase += PF) {
#pragma unroll
        for (int j = 0; j < PF; ++j) {
            const int d = dbase + j;
            float B0 = fB0[j], B1 = fB1[j], E0 = fE0[j], E1 = fE1[j];
            const int dn = d + PF;
            fB0[j] = Bb[rB0 + cl(dn - 1 - u0)];
            fB1[j] = Bb[rB1 + cl(dn - 1 - u1)];
            fE0[j] = Eb[rE0 + cl(dn - u0)];
            fE1[j] = Eb[rE1 + cl(dn - 1 - u0)];

            float t1lo = aLo + B0;
            float t2lo = (lane == 0) ? NEG : aHiLeft + E0;
            float t1hi = aHi + B1;
            float t2hi = aLo + E1;

            bool okLo = (u0 <= Ub) && (d >= u0) && (d <= u0 + Tb - 1);
            bool okHi = (u1 <= Ub) && (d >= u1) && (d <= u1 + Tb - 1);

            float nLo = lse2(t1lo, t2lo);
            float nHi = lse2(t1hi, t2hi);
            aLo = okLo ? nLo : aLo;
            aHi = okHi ? nHi : aHi;
            aHiLeft = __shfl_up(aHi, 1);
        }
    }

    if (u0 == Ub || u1 == Ub) {
        float aF = (u0 == Ub) ? aLo : aHi;
        out[b] = -(aF + Bb[min(Ub, U1 - 1) * TT + (Tb - 1)]);
    }
}

extern "C" void kernel_launch(void* const* d_in, const int* in_sizes, int n_in,
                              void* d_out, int out_size, void* d_ws, size_t ws_size,
                              hipStream_t stream) {
    const float* logits = (const float*)d_in[0];
    const int* targets  = (const int*)d_in[1];
    const int* tlen     = (const int*)d_in[2];
    const int* ulen     = (const int*)d_in[3];
    float* out = (float*)d_out;

    float* lpB = (float*)d_ws;
    float* lpE = lpB + (size_t)BB * U1 * TT;

    int waves  = BB * (TT / 2) * U1;
    int blocks = (waves + 3) / 4;
    k_lse<<<blocks, 256, 0, stream>>>(logits, targets, lpB, lpE);
    k_dp<<<BB, 64, 0, stream>>>(lpB, lpE, tlen, ulen, out);
}